// Round 5
// baseline (105.965 us; speedup 1.0000x reference)
//
#include <hip/hip_runtime.h>
#include <hip/hip_fp16.h>
#include <math.h>

#define N_ATOMS 21
#define DESC 210
#define ASTR 216            // zero-padded A row stride (27 x 8-f32 slices)
#define T_ROWS 12000
#define BATCH 64
#define NCH_A 188           // k_A chunks of 64 t
#define NCH_C 256           // k_C t-chunks
#define TC_C 47             // 256*47 = 12032 >= 12000

#define QCONST 0.22360679774997896f   // sqrt(5)/10
#define K0CONST (1.0f/60.0f)          // 5/(3*sig^2)

__device__ __forceinline__ float u2f(unsigned int u) {
    union { unsigned int u; float f; } x; x.u = u; return x.f;
}
__device__ __forceinline__ unsigned short f2bf(float f) {
    union { float f; unsigned int u; } x; x.f = f;
    unsigned int r = x.u + 0x7fffu + ((x.u >> 16) & 1u);  // RNE-ish
    return (unsigned short)(r >> 16);
}

// ---------------- k_prep: A[m][216] = q/dist (zero-padded), na2 ----------------
__global__ __launch_bounds__(256) void k_prep(const float* __restrict__ Rs,
                                              float* __restrict__ A,
                                              float* __restrict__ na2) {
    int m = blockIdx.x;
    __shared__ float R[N_ATOMS * 3];
    __shared__ float red[256];
    int tid = threadIdx.x;
    if (tid < N_ATOMS * 3) R[tid] = Rs[m * N_ATOMS * 3 + tid];
    __syncthreads();
    float val = 0.f;
    if (tid < DESC) {
        int p = tid;
        int i = (int)((1.0f + sqrtf(1.0f + 8.0f * (float)p)) * 0.5f);
        while (i * (i - 1) / 2 > p) --i;
        while ((i + 1) * i / 2 <= p) ++i;
        int j = p - i * (i - 1) / 2;
        float dx = R[i * 3 + 0] - R[j * 3 + 0];
        float dy = R[i * 3 + 1] - R[j * 3 + 1];
        float dz = R[i * 3 + 2] - R[j * 3 + 2];
        float d = sqrtf(dx * dx + dy * dy + dz * dz);
        val = QCONST / d;
        A[m * ASTR + tid] = val;
    } else if (tid < ASTR) {
        A[m * ASTR + tid] = 0.f;
    }
    red[tid] = val * val;
    __syncthreads();
    for (int s = 128; s > 0; s >>= 1) {
        if (tid < s) red[tid] += red[tid + s];
        __syncthreads();
    }
    if (tid == 0) na2[m] = red[0];
}

// ---------------- k_A: P=a.b, Q=a.j via LDS-staged bf16 B/J chunk ----------------
// 188 blocks x 512 thr (8 waves x 8-m groups). lane = t-in-chunk.
// LDS rows 512B, XOR-swizzled 16B slots: byte ^= ((row&7)<<4) -> conflict-free b128.
__global__ __launch_bounds__(512) void k_A(const float* __restrict__ Btr,
                                           const float* __restrict__ Jx,
                                           const float* __restrict__ A,
                                           const float* __restrict__ na2,
                                           float* __restrict__ w12,   // [T][128]: w1q | w2
                                           float* __restrict__ es_p,  // [NCH_A][64]
                                           float* __restrict__ rs_p) {
    __shared__ unsigned char lds[2 * 64 * 512];  // B rows then J rows
    const int chunk = blockIdx.x;
    const int tid = threadIdx.x;
    const int lane = tid & 63;
    const int mg = __builtin_amdgcn_readfirstlane(tid >> 6);  // 0..7
    const int t0 = chunk * 64;

    // ---- stage: 2 arrays x 64 rows x 108 4B-granules (210 data + zero pad) ----
    for (int g = tid; g < 2 * 64 * 108; g += 512) {
        int arr = (g >= 6912) ? 1 : 0;
        int g2 = g - arr * 6912;
        int r = g2 / 108;
        int c = g2 - r * 108;
        int tr = t0 + r;
        if (tr >= T_ROWS) tr = T_ROWS - 1;
        const float* src = arr ? Jx : Btr;
        float2 v = make_float2(0.f, 0.f);
        if (c < 105) v = *(const float2*)(src + (size_t)tr * DESC + 2 * c);
        unsigned int packed = (unsigned int)f2bf(v.x) | ((unsigned int)f2bf(v.y) << 16);
        int byte = arr * 32768 + r * 512 + ((4 * c) ^ ((r & 7) << 4));
        *(unsigned int*)(lds + byte) = packed;
    }
    __syncthreads();

    const int t = t0 + lane;
    const float tmask = (t < T_ROWS) ? 1.f : 0.f;
    float P[8], Q[8];
#pragma unroll
    for (int k = 0; k < 8; k++) { P[k] = 0.f; Q[k] = 0.f; }
    float nb = 0.f, bjr = 0.f;
    const unsigned char* rb = lds + lane * 512;
    const unsigned char* rj = rb + 32768;
    const int sw = (lane & 7) << 4;
    const float* Am = A + mg * 8 * ASTR;

#pragma unroll 3
    for (int k8 = 0; k8 < 27; k8++) {
        const int off = (k8 * 16) ^ sw;
        uint4 bw = *(const uint4*)(rb + off);
        uint4 jw = *(const uint4*)(rj + off);
        float b[8], j[8];
        b[0] = u2f(bw.x << 16); b[1] = u2f(bw.x & 0xFFFF0000u);
        b[2] = u2f(bw.y << 16); b[3] = u2f(bw.y & 0xFFFF0000u);
        b[4] = u2f(bw.z << 16); b[5] = u2f(bw.z & 0xFFFF0000u);
        b[6] = u2f(bw.w << 16); b[7] = u2f(bw.w & 0xFFFF0000u);
        j[0] = u2f(jw.x << 16); j[1] = u2f(jw.x & 0xFFFF0000u);
        j[2] = u2f(jw.y << 16); j[3] = u2f(jw.y & 0xFFFF0000u);
        j[4] = u2f(jw.z << 16); j[5] = u2f(jw.z & 0xFFFF0000u);
        j[6] = u2f(jw.w << 16); j[7] = u2f(jw.w & 0xFFFF0000u);
#pragma unroll
        for (int k = 0; k < 8; k++) {
            nb = fmaf(b[k], b[k], nb);
            bjr = fmaf(b[k], j[k], bjr);
        }
#pragma unroll
        for (int m = 0; m < 8; m++) {
            const float* ar = Am + m * ASTR + k8 * 8;  // wave-uniform -> s_load
#pragma unroll
            for (int k = 0; k < 8; k++) {
                P[m] = fmaf(ar[k], b[k], P[m]);
                Q[m] = fmaf(ar[k], j[k], Q[m]);
            }
        }
    }

    float es[8], rs[8], w1q[8], w2a[8];
#pragma unroll
    for (int m = 0; m < 8; m++) {
        float S = na2[mg * 8 + m] + QCONST * QCONST * nb - 2.f * QCONST * P[m];
        S = fmaxf(S, 0.f);
        float xd = sqrtf(S);
        float e = K0CONST * __expf(-xd);
        float dot = (Q[m] - QCONST * bjr) * tmask;
        float w1 = e * dot;
        float w2 = e * (1.f + xd);
        w1q[m] = QCONST * w1;
        w2a[m] = w2;
        es[m] = w2 * dot;
        rs[m] = w1;
    }
    if (t < T_ROWS) {
        float* wr = w12 + (size_t)t * 128 + mg * 8;
        *(float4*)(wr) = make_float4(w1q[0], w1q[1], w1q[2], w1q[3]);
        *(float4*)(wr + 4) = make_float4(w1q[4], w1q[5], w1q[6], w1q[7]);
        *(float4*)(wr + 64) = make_float4(w2a[0], w2a[1], w2a[2], w2a[3]);
        *(float4*)(wr + 68) = make_float4(w2a[4], w2a[5], w2a[6], w2a[7]);
    }
#pragma unroll
    for (int mask = 1; mask < 64; mask <<= 1) {
#pragma unroll
        for (int m = 0; m < 8; m++) {
            es[m] += __shfl_xor(es[m], mask);
            rs[m] += __shfl_xor(rs[m], mask);
        }
    }
    if (lane == 0) {
#pragma unroll
        for (int m = 0; m < 8; m++) {
            es_p[chunk * 64 + mg * 8 + m] = es[m];
            rs_p[chunk * 64 + mg * 8 + m] = rs[m];
        }
    }
}

// ---------------- k_C: partial F[m][d] per t-chunk; lane=m, wave=d-slice ----------------
// 256 blocks x 896 thr (14 waves x 15 d). w loads coalesced, B/J loads uniform (s_load).
__global__ __launch_bounds__(896) void k_C(const float* __restrict__ Btr,
                                           const float* __restrict__ Jx,
                                           const float* __restrict__ w12,
                                           __half* __restrict__ pC) {  // [c][m][210]
    const int c = blockIdx.x;
    const int tid = threadIdx.x;
    const int lane = tid & 63;                                  // m
    const int wv = __builtin_amdgcn_readfirstlane(tid >> 6);    // 0..13
    const int d0 = wv * 15;
    const int tstart = c * TC_C;
    const int tend = min(tstart + TC_C, T_ROWS);

    float acc[15];
#pragma unroll
    for (int k = 0; k < 15; k++) acc[k] = 0.f;

#pragma unroll 2
    for (int t = tstart; t < tend; ++t) {
        float w1 = w12[(size_t)t * 128 + lane];
        float w2 = w12[(size_t)t * 128 + 64 + lane];
        const float* bp = Btr + (size_t)t * DESC + d0;  // uniform -> s_load
        const float* jp = Jx + (size_t)t * DESC + d0;
#pragma unroll
        for (int k = 0; k < 15; k++)
            acc[k] = fmaf(w1, bp[k], fmaf(w2, jp[k], acc[k]));
    }
    __half* op = pC + ((size_t)c * 64 + lane) * DESC + d0;
#pragma unroll
    for (int k = 0; k < 15; k++) op[k] = __float2half(acc[k]);
}

// ---------------- k_final: coalesced c-reduction + forces + energy ----------------
__global__ __launch_bounds__(256) void k_final(const float* __restrict__ Rs,
                                               const float* __restrict__ A,
                                               const float* __restrict__ es_p,
                                               const float* __restrict__ rs_p,
                                               const __half* __restrict__ pC,
                                               float* __restrict__ out) {
    const int m = blockIdx.x;
    const int tid = threadIdx.x;
    __shared__ float fsx[DESC];
    __shared__ float R[N_ATOMS * 3];
    __shared__ float s_rs, s_es;
    if (tid < N_ATOMS * 3) R[tid] = Rs[m * N_ATOMS * 3 + tid];
    if (tid >= 192) {  // wave 3: es/rs reduction (overlaps waves 0-2's pC loop)
        int l = tid - 192;
        float es = 0.f, rs = 0.f;
        for (int c2 = l; c2 < NCH_A; c2 += 64) {
            es += es_p[c2 * 64 + m];
            rs += rs_p[c2 * 64 + m];
        }
        for (int mask = 1; mask < 64; mask <<= 1) {
            es += __shfl_xor(es, mask);
            rs += __shfl_xor(rs, mask);
        }
        if (l == 0) { s_es = es; s_rs = rs; }
    }
    float s = 0.f;
    if (tid < DESC) {
#pragma unroll 4
        for (int c2 = 0; c2 < NCH_C; c2++)
            s += __half2float(pC[((size_t)c2 * 64 + m) * DESC + tid]);
    }
    __syncthreads();
    if (tid < DESC) fsx[tid] = s_rs * A[m * ASTR + tid] - s;  // STD = 1
    if (tid == 0) out[m] = s_es * (1.0f / QCONST);            // Es = sum/q, C=0
    __syncthreads();
    if (tid < N_ATOMS * 3) {
        int b = tid / 3, kk = tid % 3;
        float acc = 0.f;
        for (int a = 0; a < N_ATOMS; a++) {
            if (a == b) continue;
            float dx = R[a * 3 + 0] - R[b * 3 + 0];
            float dy = R[a * 3 + 1] - R[b * 3 + 1];
            float dz = R[a * 3 + 2] - R[b * 3 + 2];
            float d2 = dx * dx + dy * dy + dz * dz;
            float dist = sqrtf(d2);
            float inv3 = 1.0f / (d2 * dist);
            int hi = (a > b) ? a : b, lo = (a > b) ? b : a;
            int p = hi * (hi - 1) / 2 + lo;
            float diffk = (kk == 0) ? dx : ((kk == 1) ? dy : dz);
            acc = fmaf(fsx[p] * inv3, diffk, acc);
        }
        out[BATCH + m * N_ATOMS * 3 + tid] = acc;
    }
}

extern "C" void kernel_launch(void* const* d_in, const int* in_sizes, int n_in,
                              void* d_out, int out_size, void* d_ws, size_t ws_size,
                              hipStream_t stream) {
    (void)in_sizes; (void)n_in; (void)out_size; (void)ws_size;
    const float* Rs = (const float*)d_in[0];
    const float* Btr = (const float*)d_in[1];
    const float* Jx = (const float*)d_in[2];
    float* out = (float*)d_out;

    float* A = (float*)d_ws;                   // 64*216
    float* na2 = A + BATCH * ASTR;             // 64
    float* w12 = na2 + BATCH;                  // 12000*128
    float* es_p = w12 + (size_t)T_ROWS * 128;  // 188*64
    float* rs_p = es_p + NCH_A * 64;           // 188*64
    __half* pC = (__half*)(rs_p + NCH_A * 64); // 256*64*210 halfs

    k_prep<<<dim3(BATCH), dim3(256), 0, stream>>>(Rs, A, na2);
    k_A<<<dim3(NCH_A), dim3(512), 0, stream>>>(Btr, Jx, A, na2, w12, es_p, rs_p);
    k_C<<<dim3(NCH_C), dim3(896), 0, stream>>>(Btr, Jx, w12, pC);
    k_final<<<dim3(BATCH), dim3(256), 0, stream>>>(Rs, A, es_p, rs_p, pC, out);
}

// Round 6
// 105.734 us; speedup vs baseline: 1.0022x; 1.0022x over previous
//
#include <hip/hip_runtime.h>
#include <hip/hip_fp16.h>
#include <math.h>

#define N_ATOMS 21
#define DESC 210
#define ASTR 216            // zero-padded A row stride (27 x 8-f32 slices)
#define T_ROWS 12000
#define BATCH 64
#define NCH_A 188           // k_A chunks of 64 t
#define NCH_C 256           // k_C t-chunks
#define TC_C 47             // 256*47 = 12032 >= 12000

#define QCONST 0.22360679774997896f   // sqrt(5)/10
#define K0CONST (1.0f/60.0f)          // 5/(3*sig^2)

__device__ __forceinline__ float u2f(unsigned int u) {
    union { unsigned int u; float f; } x; x.u = u; return x.f;
}
__device__ __forceinline__ unsigned short f2bf(float f) {
    union { float f; unsigned int u; } x; x.f = f;
    unsigned int r = x.u + 0x7fffu + ((x.u >> 16) & 1u);  // RNE-ish
    return (unsigned short)(r >> 16);
}

// ---------------- k_prep: A[m][216] = q/dist (zero-padded), na2 ----------------
__global__ __launch_bounds__(256) void k_prep(const float* __restrict__ Rs,
                                              float* __restrict__ A,
                                              float* __restrict__ na2) {
    int m = blockIdx.x;
    __shared__ float R[N_ATOMS * 3];
    __shared__ float red[256];
    int tid = threadIdx.x;
    if (tid < N_ATOMS * 3) R[tid] = Rs[m * N_ATOMS * 3 + tid];
    __syncthreads();
    float val = 0.f;
    if (tid < DESC) {
        int p = tid;
        int i = (int)((1.0f + sqrtf(1.0f + 8.0f * (float)p)) * 0.5f);
        while (i * (i - 1) / 2 > p) --i;
        while ((i + 1) * i / 2 <= p) ++i;
        int j = p - i * (i - 1) / 2;
        float dx = R[i * 3 + 0] - R[j * 3 + 0];
        float dy = R[i * 3 + 1] - R[j * 3 + 1];
        float dz = R[i * 3 + 2] - R[j * 3 + 2];
        float d = sqrtf(dx * dx + dy * dy + dz * dz);
        val = QCONST / d;
        A[m * ASTR + tid] = val;
    } else if (tid < ASTR) {
        A[m * ASTR + tid] = 0.f;
    }
    red[tid] = val * val;
    __syncthreads();
    for (int s = 128; s > 0; s >>= 1) {
        if (tid < s) red[tid] += red[tid + s];
        __syncthreads();
    }
    if (tid == 0) na2[m] = red[0];
}

// ---------------- k_A: P=a.b, Q=a.j via LDS-staged bf16 B/J chunk ----------------
// 188 blocks x 512 thr (8 waves x 8-m groups). lane = t-in-chunk.
// LDS rows 512B, XOR-swizzled 16B slots: byte ^= ((row&7)<<4) -> conflict-free b128.
__global__ __launch_bounds__(512) void k_A(const float* __restrict__ Btr,
                                           const float* __restrict__ Jx,
                                           const float* __restrict__ A,
                                           const float* __restrict__ na2,
                                           float* __restrict__ w12,   // [T][128]: w1q | w2
                                           float* __restrict__ es_p,  // [NCH_A][64]
                                           float* __restrict__ rs_p) {
    __shared__ unsigned char lds[2 * 64 * 512];  // B rows then J rows
    const int chunk = blockIdx.x;
    const int tid = threadIdx.x;
    const int lane = tid & 63;
    const int mg = __builtin_amdgcn_readfirstlane(tid >> 6);  // 0..7
    const int t0 = chunk * 64;

    // ---- stage: 2 arrays x 64 rows x 108 4B-granules (210 data + zero pad) ----
    for (int g = tid; g < 2 * 64 * 108; g += 512) {
        int arr = (g >= 6912) ? 1 : 0;
        int g2 = g - arr * 6912;
        int r = g2 / 108;
        int c = g2 - r * 108;
        int tr = t0 + r;
        if (tr >= T_ROWS) tr = T_ROWS - 1;
        const float* src = arr ? Jx : Btr;
        float2 v = make_float2(0.f, 0.f);
        if (c < 105) v = *(const float2*)(src + (size_t)tr * DESC + 2 * c);
        unsigned int packed = (unsigned int)f2bf(v.x) | ((unsigned int)f2bf(v.y) << 16);
        int byte = arr * 32768 + r * 512 + ((4 * c) ^ ((r & 7) << 4));
        *(unsigned int*)(lds + byte) = packed;
    }
    __syncthreads();

    const int t = t0 + lane;
    const float tmask = (t < T_ROWS) ? 1.f : 0.f;
    float P[8], Q[8];
#pragma unroll
    for (int k = 0; k < 8; k++) { P[k] = 0.f; Q[k] = 0.f; }
    float nb = 0.f, bjr = 0.f;
    const unsigned char* rb = lds + lane * 512;
    const unsigned char* rj = rb + 32768;
    const int sw = (lane & 7) << 4;
    const float* Am = A + mg * 8 * ASTR;

#pragma unroll 3
    for (int k8 = 0; k8 < 27; k8++) {
        const int off = (k8 * 16) ^ sw;
        uint4 bw = *(const uint4*)(rb + off);
        uint4 jw = *(const uint4*)(rj + off);
        float b[8], j[8];
        b[0] = u2f(bw.x << 16); b[1] = u2f(bw.x & 0xFFFF0000u);
        b[2] = u2f(bw.y << 16); b[3] = u2f(bw.y & 0xFFFF0000u);
        b[4] = u2f(bw.z << 16); b[5] = u2f(bw.z & 0xFFFF0000u);
        b[6] = u2f(bw.w << 16); b[7] = u2f(bw.w & 0xFFFF0000u);
        j[0] = u2f(jw.x << 16); j[1] = u2f(jw.x & 0xFFFF0000u);
        j[2] = u2f(jw.y << 16); j[3] = u2f(jw.y & 0xFFFF0000u);
        j[4] = u2f(jw.z << 16); j[5] = u2f(jw.z & 0xFFFF0000u);
        j[6] = u2f(jw.w << 16); j[7] = u2f(jw.w & 0xFFFF0000u);
#pragma unroll
        for (int k = 0; k < 8; k++) {
            nb = fmaf(b[k], b[k], nb);
            bjr = fmaf(b[k], j[k], bjr);
        }
#pragma unroll
        for (int m = 0; m < 8; m++) {
            const float* ar = Am + m * ASTR + k8 * 8;  // wave-uniform -> s_load
#pragma unroll
            for (int k = 0; k < 8; k++) {
                P[m] = fmaf(ar[k], b[k], P[m]);
                Q[m] = fmaf(ar[k], j[k], Q[m]);
            }
        }
    }

    float es[8], rs[8], w1q[8], w2a[8];
#pragma unroll
    for (int m = 0; m < 8; m++) {
        float S = na2[mg * 8 + m] + QCONST * QCONST * nb - 2.f * QCONST * P[m];
        S = fmaxf(S, 0.f);
        float xd = sqrtf(S);
        float e = K0CONST * __expf(-xd);
        float dot = (Q[m] - QCONST * bjr) * tmask;
        float w1 = e * dot;
        float w2 = e * (1.f + xd);
        w1q[m] = QCONST * w1;
        w2a[m] = w2;
        es[m] = w2 * dot;
        rs[m] = w1;
    }
    if (t < T_ROWS) {
        float* wr = w12 + (size_t)t * 128 + mg * 8;
        *(float4*)(wr) = make_float4(w1q[0], w1q[1], w1q[2], w1q[3]);
        *(float4*)(wr + 4) = make_float4(w1q[4], w1q[5], w1q[6], w1q[7]);
        *(float4*)(wr + 64) = make_float4(w2a[0], w2a[1], w2a[2], w2a[3]);
        *(float4*)(wr + 68) = make_float4(w2a[4], w2a[5], w2a[6], w2a[7]);
    }
#pragma unroll
    for (int mask = 1; mask < 64; mask <<= 1) {
#pragma unroll
        for (int m = 0; m < 8; m++) {
            es[m] += __shfl_xor(es[m], mask);
            rs[m] += __shfl_xor(rs[m], mask);
        }
    }
    if (lane == 0) {
#pragma unroll
        for (int m = 0; m < 8; m++) {
            es_p[chunk * 64 + mg * 8 + m] = es[m];
            rs_p[chunk * 64 + mg * 8 + m] = rs[m];
        }
    }
}

// ---------------- k_C: partial F[m][d] per t-chunk; lane=m, wave=d-slice ----------------
// 256 blocks x 896 thr (14 waves x 15 d). w loads coalesced, B/J loads uniform (s_load).
__global__ __launch_bounds__(896) void k_C(const float* __restrict__ Btr,
                                           const float* __restrict__ Jx,
                                           const float* __restrict__ w12,
                                           __half* __restrict__ pC) {  // [c][m][210]
    const int c = blockIdx.x;
    const int tid = threadIdx.x;
    const int lane = tid & 63;                                  // m
    const int wv = __builtin_amdgcn_readfirstlane(tid >> 6);    // 0..13
    const int d0 = wv * 15;
    const int tstart = c * TC_C;
    const int tend = min(tstart + TC_C, T_ROWS);

    float acc[15];
#pragma unroll
    for (int k = 0; k < 15; k++) acc[k] = 0.f;

#pragma unroll 2
    for (int t = tstart; t < tend; ++t) {
        float w1 = w12[(size_t)t * 128 + lane];
        float w2 = w12[(size_t)t * 128 + 64 + lane];
        const float* bp = Btr + (size_t)t * DESC + d0;  // uniform -> s_load
        const float* jp = Jx + (size_t)t * DESC + d0;
#pragma unroll
        for (int k = 0; k < 15; k++)
            acc[k] = fmaf(w1, bp[k], fmaf(w2, jp[k], acc[k]));
    }
    __half* op = pC + ((size_t)c * 64 + lane) * DESC + d0;
#pragma unroll
    for (int k = 0; k < 15; k++) op[k] = __float2half(acc[k]);
}

// ---------------- k_final: coalesced c-reduction + forces + energy ----------------
__global__ __launch_bounds__(256) void k_final(const float* __restrict__ Rs,
                                               const float* __restrict__ A,
                                               const float* __restrict__ es_p,
                                               const float* __restrict__ rs_p,
                                               const __half* __restrict__ pC,
                                               float* __restrict__ out) {
    const int m = blockIdx.x;
    const int tid = threadIdx.x;
    __shared__ float fsx[DESC];
    __shared__ float R[N_ATOMS * 3];
    __shared__ float s_rs, s_es;
    if (tid < N_ATOMS * 3) R[tid] = Rs[m * N_ATOMS * 3 + tid];
    if (tid >= 192) {  // wave 3: es/rs reduction (overlaps waves 0-2's pC loop)
        int l = tid - 192;
        float es = 0.f, rs = 0.f;
        for (int c2 = l; c2 < NCH_A; c2 += 64) {
            es += es_p[c2 * 64 + m];
            rs += rs_p[c2 * 64 + m];
        }
        for (int mask = 1; mask < 64; mask <<= 1) {
            es += __shfl_xor(es, mask);
            rs += __shfl_xor(rs, mask);
        }
        if (l == 0) { s_es = es; s_rs = rs; }
    }
    float s = 0.f;
    if (tid < DESC) {
#pragma unroll 4
        for (int c2 = 0; c2 < NCH_C; c2++)
            s += __half2float(pC[((size_t)c2 * 64 + m) * DESC + tid]);
    }
    __syncthreads();
    if (tid < DESC) fsx[tid] = s_rs * A[m * ASTR + tid] - s;  // STD = 1
    if (tid == 0) out[m] = s_es * (1.0f / QCONST);            // Es = sum/q, C=0
    __syncthreads();
    if (tid < N_ATOMS * 3) {
        int b = tid / 3, kk = tid % 3;
        float acc = 0.f;
        for (int a = 0; a < N_ATOMS; a++) {
            if (a == b) continue;
            float dx = R[a * 3 + 0] - R[b * 3 + 0];
            float dy = R[a * 3 + 1] - R[b * 3 + 1];
            float dz = R[a * 3 + 2] - R[b * 3 + 2];
            float d2 = dx * dx + dy * dy + dz * dz;
            float dist = sqrtf(d2);
            float inv3 = 1.0f / (d2 * dist);
            int hi = (a > b) ? a : b, lo = (a > b) ? b : a;
            int p = hi * (hi - 1) / 2 + lo;
            float diffk = (kk == 0) ? dx : ((kk == 1) ? dy : dz);
            acc = fmaf(fsx[p] * inv3, diffk, acc);
        }
        out[BATCH + m * N_ATOMS * 3 + tid] = acc;
    }
}

extern "C" void kernel_launch(void* const* d_in, const int* in_sizes, int n_in,
                              void* d_out, int out_size, void* d_ws, size_t ws_size,
                              hipStream_t stream) {
    (void)in_sizes; (void)n_in; (void)out_size; (void)ws_size;
    const float* Rs = (const float*)d_in[0];
    const float* Btr = (const float*)d_in[1];
    const float* Jx = (const float*)d_in[2];
    float* out = (float*)d_out;

    float* A = (float*)d_ws;                   // 64*216
    float* na2 = A + BATCH * ASTR;             // 64
    float* w12 = na2 + BATCH;                  // 12000*128
    float* es_p = w12 + (size_t)T_ROWS * 128;  // 188*64
    float* rs_p = es_p + NCH_A * 64;           // 188*64
    __half* pC = (__half*)(rs_p + NCH_A * 64); // 256*64*210 halfs

    k_prep<<<dim3(BATCH), dim3(256), 0, stream>>>(Rs, A, na2);
    k_A<<<dim3(NCH_A), dim3(512), 0, stream>>>(Btr, Jx, A, na2, w12, es_p, rs_p);
    k_C<<<dim3(NCH_C), dim3(896), 0, stream>>>(Btr, Jx, w12, pC);
    k_final<<<dim3(BATCH), dim3(256), 0, stream>>>(Rs, A, es_p, rs_p, pC, out);
}